// Round 4
// baseline (5626.454 us; speedup 1.0000x reference)
//
#include <hip/hip_runtime.h>

#define DIM 64
#define HID 256
#define NSTEPS 100
#define DT (1.0f / 100.0f)

typedef __attribute__((ext_vector_type(8))) short short8;   // 8 bf16 (MFMA A/B frag)
typedef __attribute__((ext_vector_type(4))) float floatx4;  // MFMA C/D frag

__device__ __forceinline__ unsigned int rne_hi(unsigned int u) {
  // bf16 RNE result left in high 16 bits
  return u + 0x7fffu + ((u >> 16) & 1u);
}
__device__ __forceinline__ unsigned short f2bf(float f) {
  union { float f; unsigned int u; } v; v.f = f;
  return (unsigned short)(rne_hi(v.u) >> 16);
}
// pack2: bf16(a) in low half, bf16(b) in high half — one v_perm_b32
__device__ __forceinline__ unsigned int pack2(float a, float b) {
  union { float f; unsigned int u; } x, y; x.f = a; y.f = b;
  return __builtin_amdgcn_perm(rne_hi(y.u), rne_hi(x.u), 0x07060302);
}
__device__ __forceinline__ float u2f(unsigned int u) {
  union { unsigned int u; float f; } v; v.u = u; return v.f;
}
__device__ __forceinline__ float fast_tanh(float x) {
  float e = __expf(2.0f * x);
  return 1.0f - 2.0f * __builtin_amdgcn_rcpf(e + 1.0f);
}

// Repack W (K x N row-major fp32) into frag-major bf16 (A-frag of W^T).
__global__ void prep_weights(const float* __restrict__ W1,
                             const float* __restrict__ W2,
                             const float* __restrict__ W3,
                             unsigned short* __restrict__ ws) {
  int e = blockIdx.x * 256 + threadIdx.x;  // 98304 total
  const float* src; int N, ntile, el, base;
  if (e < 16384)      { src = W1; N = 256; ntile = 16; base = 0;     el = e; }
  else if (e < 81920) { src = W2; N = 256; ntile = 16; base = 16384; el = e - 16384; }
  else                { src = W3; N = 64;  ntile = 4;  base = 81920; el = e - 81920; }
  int j = el & 7;
  int l = (el >> 3) & 63;
  int rem = el >> 9;
  int t = rem % ntile;
  int s = rem / ntile;
  int k = s * 32 + ((l >> 4) << 3) + j;
  int n = t * 16 + (l & 15);
  ws[base + el] = f2bf(src[k * N + n]);
}

// Transposed frame: M = features (weights = A operand, register-resident),
// N = batch (activations = B operand, [n][k] in LDS, XOR-swizzled 16B granules:
// physical granule pg = g ^ (row & 7); rows stay 512B/128B aligned, no pad).
// 512 threads = 8 waves; __launch_bounds__(512,4) caps regs at 128/wave so
// TWO blocks co-reside per CU (4 waves/SIMD) for cross-block overlap.
// Biases are folded into MFMA accumulator init (stored packed bf16, 10 regs).
__global__ __launch_bounds__(512, 4)
void cnf_kernel(const float* __restrict__ z0,
                const float* __restrict__ b1,
                const float* __restrict__ b2,
                const float* __restrict__ b3,
                const unsigned short* __restrict__ wsAll,
                float* __restrict__ out) {
  __shared__ __align__(16) unsigned short Zbuf[64 * 64];    // Z^T  8192 B
  __shared__ __align__(16) unsigned short Hbuf[64 * 256];   // H^T 32768 B

  const int tid  = threadIdx.x;
  const int wave = tid >> 6;
  const int lane = tid & 63;
  const int i15  = lane & 15;   // batch col within N-tile
  const int q    = lane >> 4;
  const int swz  = i15 & 7;     // XOR swizzle key (row & 7)
  const int grow = blockIdx.x * 64;
  const int mt3  = wave & 3;    // L3 M-tile
  const int ntp  = wave >> 2;   // L3 N-pair

  const unsigned short* wsW1 = wsAll;
  const unsigned short* wsW2 = wsAll + 16384;
  const unsigned short* wsW3 = wsAll + 81920;

  // ---- register-resident weight A-frags (48 VGPR) ----
  short8 w1f[2][2], w2f[8][2], w3f[8];
#pragma unroll
  for (int s = 0; s < 2; ++s)
#pragma unroll
    for (int tt = 0; tt < 2; ++tt)
      w1f[s][tt] = *(const short8*)&wsW1[((s * 16 + 2 * wave + tt) * 64 + lane) * 8];
#pragma unroll
  for (int s = 0; s < 8; ++s)
#pragma unroll
    for (int tt = 0; tt < 2; ++tt)
      w2f[s][tt] = *(const short8*)&wsW2[((s * 16 + 2 * wave + tt) * 64 + lane) * 8];
#pragma unroll
  for (int s = 0; s < 8; ++s)
    w3f[s] = *(const short8*)&wsW3[((s * 4 + mt3) * 64 + lane) * 8];

  // ---- biases packed bf16 (10 regs); used only as accumulator init ----
  unsigned int b1p[2][2], b2p[2][2], b3p[2];
#pragma unroll
  for (int tt = 0; tt < 2; ++tt) {
    float4 v1 = *(const float4*)&b1[(2 * wave + tt) * 16 + q * 4];
    float4 v2 = *(const float4*)&b2[(2 * wave + tt) * 16 + q * 4];
    b1p[tt][0] = pack2(v1.x, v1.y); b1p[tt][1] = pack2(v1.z, v1.w);
    b2p[tt][0] = pack2(v2.x, v2.y); b2p[tt][1] = pack2(v2.z, v2.w);
  }
  {
    float4 v3 = *(const float4*)&b3[mt3 * 16 + q * 4];
    b3p[0] = pack2(v3.x, v3.y); b3p[1] = pack2(v3.z, v3.w);
  }

  // ---- RK4 state: lane holds features mt3*16+q*4..+3 of rows nt*16+i15 ----
  float z[8], zacc[8];
  {
    const int wpg = (mt3 * 2 + (q >> 1)) ^ swz;   // Zbuf write granule
    const int wof = (q & 1) * 4;
#pragma unroll
    for (int j = 0; j < 2; ++j) {
      const int nt = 2 * ntp + j;
      float4 v = *(const float4*)&z0[(grow + nt * 16 + i15) * DIM + mt3 * 16 + q * 4];
      z[j * 4 + 0] = v.x; z[j * 4 + 1] = v.y; z[j * 4 + 2] = v.z; z[j * 4 + 3] = v.w;
#pragma unroll
      for (int r = 0; r < 4; ++r) zacc[j * 4 + r] = 0.f;
      uint2 p; p.x = pack2(v.x, v.y); p.y = pack2(v.z, v.w);
      *(uint2*)&Zbuf[(nt * 16 + i15) * 64 + wpg * 8 + wof] = p;
    }
  }

  const float DT6 = DT / 6.0f, DT3 = DT / 3.0f, DTH = 0.5f * DT;
  const int hpgw = ((2 * wave) * 2 + (q >> 1));   // Hbuf write granule base (pre-XOR, tt adds 2)
  const int zpgw = (mt3 * 2 + (q >> 1)) ^ swz;
  const int wof  = (q & 1) * 4;

#pragma unroll 1
  for (int it = 0; it < NSTEPS * 4; ++it) {
    const int st = it & 3;
    __syncthreads();  // B1: Zbuf stage visible; prev L3 reads of Hbuf done

    // ---- Layer 1: K=64, acc init = b1 ----
    floatx4 acc[2][4];
#pragma unroll
    for (int tt = 0; tt < 2; ++tt) {
      float u0 = u2f(b1p[tt][0] << 16), u1 = u2f(b1p[tt][0] & 0xffff0000u);
      float u2 = u2f(b1p[tt][1] << 16), u3 = u2f(b1p[tt][1] & 0xffff0000u);
#pragma unroll
      for (int nt = 0; nt < 4; ++nt) acc[tt][nt] = floatx4{u0, u1, u2, u3};
    }
#pragma unroll
    for (int s = 0; s < 2; ++s)
#pragma unroll
      for (int nt = 0; nt < 4; ++nt) {
        const int pg = (s * 4 + q) ^ swz;
        short8 bz = *(const short8*)&Zbuf[(nt * 16 + i15) * 64 + pg * 8];
        acc[0][nt] = __builtin_amdgcn_mfma_f32_16x16x32_bf16(w1f[s][0], bz, acc[0][nt], 0, 0, 0);
        acc[1][nt] = __builtin_amdgcn_mfma_f32_16x16x32_bf16(w1f[s][1], bz, acc[1][nt], 0, 0, 0);
      }
#pragma unroll
    for (int tt = 0; tt < 2; ++tt) {
      const int pg = (hpgw + tt * 2) ^ swz;
#pragma unroll
      for (int nt = 0; nt < 4; ++nt) {
        float h0 = fast_tanh(acc[tt][nt][0]);
        float h1 = fast_tanh(acc[tt][nt][1]);
        float h2 = fast_tanh(acc[tt][nt][2]);
        float h3 = fast_tanh(acc[tt][nt][3]);
        uint2 p; p.x = pack2(h0, h1); p.y = pack2(h2, h3);
        *(uint2*)&Hbuf[(nt * 16 + i15) * 256 + pg * 8 + wof] = p;
      }
    }
    __syncthreads();  // B2: H1 visible

    // ---- Layer 2: K=256, acc init = b2 ----
    floatx4 acc2[2][4];
#pragma unroll
    for (int tt = 0; tt < 2; ++tt) {
      float u0 = u2f(b2p[tt][0] << 16), u1 = u2f(b2p[tt][0] & 0xffff0000u);
      float u2 = u2f(b2p[tt][1] << 16), u3 = u2f(b2p[tt][1] & 0xffff0000u);
#pragma unroll
      for (int nt = 0; nt < 4; ++nt) acc2[tt][nt] = floatx4{u0, u1, u2, u3};
    }
#pragma unroll
    for (int s = 0; s < 8; ++s)
#pragma unroll
      for (int nt = 0; nt < 4; ++nt) {
        const int pg = (s * 4 + q) ^ swz;
        short8 bh = *(const short8*)&Hbuf[(nt * 16 + i15) * 256 + pg * 8];
        acc2[0][nt] = __builtin_amdgcn_mfma_f32_16x16x32_bf16(w2f[s][0], bh, acc2[0][nt], 0, 0, 0);
        acc2[1][nt] = __builtin_amdgcn_mfma_f32_16x16x32_bf16(w2f[s][1], bh, acc2[1][nt], 0, 0, 0);
      }
    __syncthreads();  // B3: all H1 reads done -> Hbuf may be overwritten

#pragma unroll
    for (int tt = 0; tt < 2; ++tt) {
      const int pg = (hpgw + tt * 2) ^ swz;
#pragma unroll
      for (int nt = 0; nt < 4; ++nt) {
        float h0 = fast_tanh(acc2[tt][nt][0]);
        float h1 = fast_tanh(acc2[tt][nt][1]);
        float h2 = fast_tanh(acc2[tt][nt][2]);
        float h3 = fast_tanh(acc2[tt][nt][3]);
        uint2 p; p.x = pack2(h0, h1); p.y = pack2(h2, h3);
        *(uint2*)&Hbuf[(nt * 16 + i15) * 256 + pg * 8 + wof] = p;
      }
    }
    __syncthreads();  // B4: H2 visible

    // ---- Layer 3 + RK4: acc init = b3 ----
    floatx4 a3[2];
    {
      float u0 = u2f(b3p[0] << 16), u1 = u2f(b3p[0] & 0xffff0000u);
      float u2 = u2f(b3p[1] << 16), u3 = u2f(b3p[1] & 0xffff0000u);
      a3[0] = floatx4{u0, u1, u2, u3};
      a3[1] = floatx4{u0, u1, u2, u3};
    }
#pragma unroll
    for (int j = 0; j < 2; ++j) {
      const int nt = 2 * ntp + j;
#pragma unroll
      for (int s = 0; s < 8; ++s) {
        const int pg = (s * 4 + q) ^ swz;
        short8 bh = *(const short8*)&Hbuf[(nt * 16 + i15) * 256 + pg * 8];
        a3[j] = __builtin_amdgcn_mfma_f32_16x16x32_bf16(w3f[s], bh, a3[j], 0, 0, 0);
      }
    }
    const float wsum  = (st == 0 || st == 3) ? DT6 : DT3;
    const float cst   = (st == 2) ? DT : DTH;
    const bool  last  = (st == 3);
    const bool  first = (st == 0);
#pragma unroll
    for (int j = 0; j < 2; ++j) {
      const int nt = 2 * ntp + j;
      float stg[4];
#pragma unroll
      for (int r = 0; r < 4; ++r) {
        const int i = j * 4 + r;
        float k = a3[j][r];
        float za = first ? z[i] : zacc[i];
        za += wsum * k;
        zacc[i] = za;
        if (last) { z[i] = za; stg[r] = za; }
        else      { stg[r] = z[i] + cst * k; }
      }
      uint2 p; p.x = pack2(stg[0], stg[1]); p.y = pack2(stg[2], stg[3]);
      *(uint2*)&Zbuf[(nt * 16 + i15) * 64 + zpgw * 8 + wof] = p;
    }
  }

  // ---- final store ----
#pragma unroll
  for (int j = 0; j < 2; ++j) {
    const int nt = 2 * ntp + j;
    float4 v;
    v.x = z[j * 4 + 0]; v.y = z[j * 4 + 1]; v.z = z[j * 4 + 2]; v.w = z[j * 4 + 3];
    *(float4*)&out[(grow + nt * 16 + i15) * DIM + mt3 * 16 + q * 4] = v;
  }
}

extern "C" void kernel_launch(void* const* d_in, const int* in_sizes, int n_in,
                              void* d_out, int out_size, void* d_ws, size_t ws_size,
                              hipStream_t stream) {
  const float* z0 = (const float*)d_in[0];
  const float* W1 = (const float*)d_in[1];
  const float* b1 = (const float*)d_in[2];
  const float* W2 = (const float*)d_in[3];
  const float* b2 = (const float*)d_in[4];
  const float* W3 = (const float*)d_in[5];
  const float* b3 = (const float*)d_in[6];
  unsigned short* ws = (unsigned short*)d_ws;  // 98304 bf16 = 196608 B

  prep_weights<<<384, 256, 0, stream>>>(W1, W2, W3, ws);
  cnf_kernel<<<512, 512, 0, stream>>>(z0, b1, b2, b3, ws, (float*)d_out);
}

// Round 5
// 3174.247 us; speedup vs baseline: 1.7725x; 1.7725x over previous
//
#include <hip/hip_runtime.h>
#include <hip/hip_bf16.h>

#define DIM 64
#define HID 256
#define NSTEPS 100
#define DT (1.0f / 100.0f)
#define TSCALE 2.885390081777927f   // 2*log2(e): folded into W1,W2,b1,b2

typedef __attribute__((ext_vector_type(8))) short short8;   // 8 bf16 (MFMA A/B frag)
typedef __attribute__((ext_vector_type(4))) float floatx4;  // MFMA C/D frag

__device__ __forceinline__ unsigned short f2bf(float f) {
  union { float f; unsigned int u; } v; v.f = f;
  unsigned int u = v.u;
  return (unsigned short)((u + 0x7fffu + ((u >> 16) & 1u)) >> 16);  // RNE
}
// packed f32x2 -> bf16x2 (v_cvt_pk_bf16_f32 on gfx950)
__device__ __forceinline__ unsigned int pk2(float a, float b) {
  __hip_bfloat162 h = __float22bfloat162_rn(make_float2(a, b));
  union { __hip_bfloat162 h; unsigned int u; } v; v.h = h;
  return v.u;
}
// tanh with input pre-scaled by 2*log2(e): tanh = 1 - 2/(2^y + 1)
__device__ __forceinline__ float tanh_pre(float y) {
  float e = __builtin_amdgcn_exp2f(y);
  return 1.0f - 2.0f * __builtin_amdgcn_rcpf(e + 1.0f);
}

// Repack W (K x N row-major fp32) into frag-major bf16 (A-frag of W^T).
// W1/W2 are pre-scaled by TSCALE (tanh input scale folded in).
__global__ void prep_weights(const float* __restrict__ W1,
                             const float* __restrict__ W2,
                             const float* __restrict__ W3,
                             unsigned short* __restrict__ ws) {
  int e = blockIdx.x * 256 + threadIdx.x;  // 98304 total
  const float* src; int N, ntile, el, base; float sc;
  if (e < 16384)      { src = W1; N = 256; ntile = 16; base = 0;     el = e;         sc = TSCALE; }
  else if (e < 81920) { src = W2; N = 256; ntile = 16; base = 16384; el = e - 16384; sc = TSCALE; }
  else                { src = W3; N = 64;  ntile = 4;  base = 81920; el = e - 81920; sc = 1.0f; }
  int j = el & 7;
  int l = (el >> 3) & 63;
  int rem = el >> 9;
  int t = rem % ntile;
  int s = rem / ntile;
  int k = s * 32 + ((l >> 4) << 3) + j;
  int n = t * 16 + (l & 15);
  ws[base + el] = f2bf(src[k * N + n] * sc);
}

// Transposed frame (R2 structure): M = features (weights = A operand,
// register-resident), N = batch (activations = B operand, [n][k] in LDS,
// padded rows). 512 threads = 8 waves, launch_bounds(512,2) => no spills.
// VALU diet vs R2: exp2-based tanh (scale folded into weights), bias folded
// into acc init, v_cvt_pk_bf16_f32 packing, hoisted LDS row offsets.
__global__ __launch_bounds__(512, 2)
void cnf_kernel(const float* __restrict__ z0,
                const float* __restrict__ b1,
                const float* __restrict__ b2,
                const float* __restrict__ b3,
                const unsigned short* __restrict__ wsAll,
                float* __restrict__ out) {
  constexpr int LDZ = 72;   // shorts; 144 B row stride
  constexpr int LDH = 264;  // shorts; 528 B row stride
  __shared__ __align__(16) unsigned short Zbuf[64 * LDZ];   // 9216 B
  __shared__ __align__(16) unsigned short Hbuf[64 * LDH];   // 33792 B

  const int tid  = threadIdx.x;
  const int wave = tid >> 6;
  const int lane = tid & 63;
  const int i15  = lane & 15;   // batch col within N-tile
  const int q    = lane >> 4;
  const int q8   = q * 8;
  const int grow = blockIdx.x * 64;
  const int mt3  = wave & 3;    // L3 M-tile
  const int ntp  = wave >> 2;   // L3 N-pair

  const unsigned short* wsW1 = wsAll;
  const unsigned short* wsW2 = wsAll + 16384;
  const unsigned short* wsW3 = wsAll + 81920;

  // ---- register-resident weight A-frags (112 VGPR) ----
  short8 w1f[2][2], w2f[8][2], w3f[8];
#pragma unroll
  for (int s = 0; s < 2; ++s)
#pragma unroll
    for (int tt = 0; tt < 2; ++tt)
      w1f[s][tt] = *(const short8*)&wsW1[((s * 16 + 2 * wave + tt) * 64 + lane) * 8];
#pragma unroll
  for (int s = 0; s < 8; ++s)
#pragma unroll
    for (int tt = 0; tt < 2; ++tt)
      w2f[s][tt] = *(const short8*)&wsW2[((s * 16 + 2 * wave + tt) * 64 + lane) * 8];
#pragma unroll
  for (int s = 0; s < 8; ++s)
    w3f[s] = *(const short8*)&wsW3[((s * 4 + mt3) * 64 + lane) * 8];

  // ---- biases as fp32 regs (20); b1/b2 pre-scaled; used as acc init ----
  float b1a[2][4], b2a[2][4], b3a[4];
#pragma unroll
  for (int tt = 0; tt < 2; ++tt) {
    float4 v1 = *(const float4*)&b1[(2 * wave + tt) * 16 + q * 4];
    float4 v2 = *(const float4*)&b2[(2 * wave + tt) * 16 + q * 4];
    b1a[tt][0] = v1.x * TSCALE; b1a[tt][1] = v1.y * TSCALE;
    b1a[tt][2] = v1.z * TSCALE; b1a[tt][3] = v1.w * TSCALE;
    b2a[tt][0] = v2.x * TSCALE; b2a[tt][1] = v2.y * TSCALE;
    b2a[tt][2] = v2.z * TSCALE; b2a[tt][3] = v2.w * TSCALE;
  }
  *(float4*)b3a = *(const float4*)&b3[mt3 * 16 + q * 4];

  // ---- hoisted LDS row offsets (loop-invariant) ----
  int zrd[4], hrd[4];            // read-row base (element index), per nt
#pragma unroll
  for (int nt = 0; nt < 4; ++nt) {
    zrd[nt] = (nt * 16 + i15) * LDZ;
    hrd[nt] = (nt * 16 + i15) * LDH;
  }
  const int hwr0 = (q * 4 + i15 * LDH) + (2 * wave) * 16;   // H write base (tt adds 16, nt adds 16*LDH)
  const int zwr0 = (q * 4 + i15 * LDZ) + mt3 * 16;          // Z write base (nt adds 16*LDZ)

  // ---- RK4 state ----
  float z[8], zacc[8];
#pragma unroll
  for (int j = 0; j < 2; ++j) {
    const int nt = 2 * ntp + j;
    float4 v = *(const float4*)&z0[(grow + nt * 16 + i15) * DIM + mt3 * 16 + q * 4];
    z[j * 4 + 0] = v.x; z[j * 4 + 1] = v.y; z[j * 4 + 2] = v.z; z[j * 4 + 3] = v.w;
#pragma unroll
    for (int r = 0; r < 4; ++r) zacc[j * 4 + r] = 0.f;
    uint2 p; p.x = pk2(v.x, v.y); p.y = pk2(v.z, v.w);
    *(uint2*)&Zbuf[zwr0 + nt * 16 * LDZ] = p;
  }

  const float DT6 = DT / 6.0f, DT3 = DT / 3.0f, DTH = 0.5f * DT;

#pragma unroll 1
  for (int it = 0; it < NSTEPS * 4; ++it) {
    const int st = it & 3;
    __syncthreads();  // B1: Zbuf stage visible; prev L3 reads of Hbuf done

    // ---- Layer 1: K=64, acc init = b1 (scaled) ----
    floatx4 acc[2][4];
#pragma unroll
    for (int tt = 0; tt < 2; ++tt)
#pragma unroll
      for (int nt = 0; nt < 4; ++nt)
        acc[tt][nt] = floatx4{b1a[tt][0], b1a[tt][1], b1a[tt][2], b1a[tt][3]};
#pragma unroll
    for (int s = 0; s < 2; ++s)
#pragma unroll
      for (int nt = 0; nt < 4; ++nt) {
        short8 bz = *(const short8*)&Zbuf[zrd[nt] + s * 32 + q8];
        acc[0][nt] = __builtin_amdgcn_mfma_f32_16x16x32_bf16(w1f[s][0], bz, acc[0][nt], 0, 0, 0);
        acc[1][nt] = __builtin_amdgcn_mfma_f32_16x16x32_bf16(w1f[s][1], bz, acc[1][nt], 0, 0, 0);
      }
#pragma unroll
    for (int tt = 0; tt < 2; ++tt)
#pragma unroll
      for (int nt = 0; nt < 4; ++nt) {
        uint2 p;
        p.x = pk2(tanh_pre(acc[tt][nt][0]), tanh_pre(acc[tt][nt][1]));
        p.y = pk2(tanh_pre(acc[tt][nt][2]), tanh_pre(acc[tt][nt][3]));
        *(uint2*)&Hbuf[hwr0 + tt * 16 + nt * 16 * LDH] = p;
      }
    __syncthreads();  // B2: H1 visible

    // ---- Layer 2: K=256, acc init = b2 (scaled) ----
    floatx4 acc2[2][4];
#pragma unroll
    for (int tt = 0; tt < 2; ++tt)
#pragma unroll
      for (int nt = 0; nt < 4; ++nt)
        acc2[tt][nt] = floatx4{b2a[tt][0], b2a[tt][1], b2a[tt][2], b2a[tt][3]};
#pragma unroll
    for (int s = 0; s < 8; ++s)
#pragma unroll
      for (int nt = 0; nt < 4; ++nt) {
        short8 bh = *(const short8*)&Hbuf[hrd[nt] + s * 32 + q8];
        acc2[0][nt] = __builtin_amdgcn_mfma_f32_16x16x32_bf16(w2f[s][0], bh, acc2[0][nt], 0, 0, 0);
        acc2[1][nt] = __builtin_amdgcn_mfma_f32_16x16x32_bf16(w2f[s][1], bh, acc2[1][nt], 0, 0, 0);
      }
    __syncthreads();  // B3: all H1 reads done -> Hbuf may be overwritten

#pragma unroll
    for (int tt = 0; tt < 2; ++tt)
#pragma unroll
      for (int nt = 0; nt < 4; ++nt) {
        uint2 p;
        p.x = pk2(tanh_pre(acc2[tt][nt][0]), tanh_pre(acc2[tt][nt][1]));
        p.y = pk2(tanh_pre(acc2[tt][nt][2]), tanh_pre(acc2[tt][nt][3]));
        *(uint2*)&Hbuf[hwr0 + tt * 16 + nt * 16 * LDH] = p;
      }
    __syncthreads();  // B4: H2 visible

    // ---- Layer 3 + RK4: acc init = b3 (unscaled) ----
    floatx4 a3[2];
    a3[0] = floatx4{b3a[0], b3a[1], b3a[2], b3a[3]};
    a3[1] = a3[0];
#pragma unroll
    for (int j = 0; j < 2; ++j) {
      const int nt = 2 * ntp + j;
#pragma unroll
      for (int s = 0; s < 8; ++s) {
        short8 bh = *(const short8*)&Hbuf[hrd[nt] + s * 32 + q8];
        a3[j] = __builtin_amdgcn_mfma_f32_16x16x32_bf16(w3f[s], bh, a3[j], 0, 0, 0);
      }
    }
    const float wsum  = (st == 0 || st == 3) ? DT6 : DT3;
    const float cst   = (st == 2) ? DT : DTH;
    const bool  last  = (st == 3);
    const bool  first = (st == 0);
#pragma unroll
    for (int j = 0; j < 2; ++j) {
      const int nt = 2 * ntp + j;
      float stg[4];
#pragma unroll
      for (int r = 0; r < 4; ++r) {
        const int i = j * 4 + r;
        float k = a3[j][r];
        float za = first ? z[i] : zacc[i];
        za += wsum * k;
        zacc[i] = za;
        if (last) { z[i] = za; stg[r] = za; }
        else      { stg[r] = z[i] + cst * k; }
      }
      uint2 p; p.x = pk2(stg[0], stg[1]); p.y = pk2(stg[2], stg[3]);
      *(uint2*)&Zbuf[zwr0 + nt * 16 * LDZ] = p;
    }
  }

  // ---- final store ----
#pragma unroll
  for (int j = 0; j < 2; ++j) {
    const int nt = 2 * ntp + j;
    float4 v;
    v.x = z[j * 4 + 0]; v.y = z[j * 4 + 1]; v.z = z[j * 4 + 2]; v.w = z[j * 4 + 3];
    *(float4*)&out[(grow + nt * 16 + i15) * DIM + mt3 * 16 + q * 4] = v;
  }
}

extern "C" void kernel_launch(void* const* d_in, const int* in_sizes, int n_in,
                              void* d_out, int out_size, void* d_ws, size_t ws_size,
                              hipStream_t stream) {
  const float* z0 = (const float*)d_in[0];
  const float* W1 = (const float*)d_in[1];
  const float* b1 = (const float*)d_in[2];
  const float* W2 = (const float*)d_in[3];
  const float* b2 = (const float*)d_in[4];
  const float* W3 = (const float*)d_in[5];
  const float* b3 = (const float*)d_in[6];
  unsigned short* ws = (unsigned short*)d_ws;  // 98304 bf16 = 196608 B

  prep_weights<<<384, 256, 0, stream>>>(W1, W2, W3, ws);
  cnf_kernel<<<512, 512, 0, stream>>>(z0, b1, b2, b3, ws, (float*)d_out);
}

// Round 6
// 2927.177 us; speedup vs baseline: 1.9221x; 1.0844x over previous
//
#include <hip/hip_runtime.h>
#include <hip/hip_bf16.h>

#define DIM 64
#define HID 256
#define NSTEPS 100
#define DT (1.0f / 100.0f)
#define TSCALE 2.885390081777927f   // 2*log2(e): folded into W1,W2,b1,b2

typedef __attribute__((ext_vector_type(8))) short short8;   // 8 bf16 (MFMA A/B frag)
typedef __attribute__((ext_vector_type(4))) float floatx4;  // MFMA C/D frag

__device__ __forceinline__ unsigned short f2bf(float f) {
  union { float f; unsigned int u; } v; v.f = f;
  unsigned int u = v.u;
  return (unsigned short)((u + 0x7fffu + ((u >> 16) & 1u)) >> 16);  // RNE
}
// packed f32x2 -> bf16x2 (v_cvt_pk_bf16_f32 on gfx950)
__device__ __forceinline__ unsigned int pk2(float a, float b) {
  __hip_bfloat162 h = __float22bfloat162_rn(make_float2(a, b));
  union { __hip_bfloat162 h; unsigned int u; } v; v.h = h;
  return v.u;
}
// tanh with input pre-scaled by 2*log2(e): tanh = 1 - 2/(2^y + 1)
__device__ __forceinline__ float tanh_pre(float y) {
  float e = __builtin_amdgcn_exp2f(y);
  return 1.0f - 2.0f * __builtin_amdgcn_rcpf(e + 1.0f);
}

// Repack W (K x N row-major fp32) into frag-major bf16 (A-frag of W^T).
// W1/W2 are pre-scaled by TSCALE (tanh input scale folded in).
__global__ void prep_weights(const float* __restrict__ W1,
                             const float* __restrict__ W2,
                             const float* __restrict__ W3,
                             unsigned short* __restrict__ ws) {
  int e = blockIdx.x * 256 + threadIdx.x;  // 98304 total
  const float* src; int N, ntile, el, base; float sc;
  if (e < 16384)      { src = W1; N = 256; ntile = 16; base = 0;     el = e;         sc = TSCALE; }
  else if (e < 81920) { src = W2; N = 256; ntile = 16; base = 16384; el = e - 16384; sc = TSCALE; }
  else                { src = W3; N = 64;  ntile = 4;  base = 81920; el = e - 81920; sc = 1.0f; }
  int j = el & 7;
  int l = (el >> 3) & 63;
  int rem = el >> 9;
  int t = rem % ntile;
  int s = rem / ntile;
  int k = s * 32 + ((l >> 4) << 3) + j;
  int n = t * 16 + (l & 15);
  ws[base + el] = f2bf(src[k * N + n] * sc);
}

// Transposed frame: M = features (weights = A operand, register-resident),
// N = batch (activations = B operand in LDS).
// *** Fragment-major LDS layout ***: element (batch n, feature k) lives at
//   ((nt*NS + s)*64 + l)*8 + j,  nt=n>>4, s=k>>5, l=(n&15)+16*((k>>3)&3), j=k&7
// so every MFMA B-read is a wave-contiguous 1024B ds_read_b128 (0 conflicts,
// immediate offsets) and epilogue writes are 8B uint2 at 2-way banks (free).
__global__ __launch_bounds__(512, 2)
void cnf_kernel(const float* __restrict__ z0,
                const float* __restrict__ b1,
                const float* __restrict__ b2,
                const float* __restrict__ b3,
                const unsigned short* __restrict__ wsAll,
                float* __restrict__ out) {
  __shared__ __align__(16) unsigned short Zbuf[4096];    // 4 nt * 2 s * 512   8192 B
  __shared__ __align__(16) unsigned short Hbuf[16384];   // 4 nt * 8 s * 512  32768 B

  const int tid  = threadIdx.x;
  const int wave = tid >> 6;
  const int lane = tid & 63;
  const int i15  = lane & 15;   // batch col within N-tile
  const int q    = lane >> 4;
  const int grow = blockIdx.x * 64;
  const int mt3  = wave & 3;    // L3 M-tile
  const int ntp  = wave >> 2;   // L3 N-pair

  const unsigned short* wsW1 = wsAll;
  const unsigned short* wsW2 = wsAll + 16384;
  const unsigned short* wsW3 = wsAll + 81920;

  // ---- register-resident weight A-frags (112 VGPR) ----
  short8 w1f[2][2], w2f[8][2], w3f[8];
#pragma unroll
  for (int s = 0; s < 2; ++s)
#pragma unroll
    for (int tt = 0; tt < 2; ++tt)
      w1f[s][tt] = *(const short8*)&wsW1[((s * 16 + 2 * wave + tt) * 64 + lane) * 8];
#pragma unroll
  for (int s = 0; s < 8; ++s)
#pragma unroll
    for (int tt = 0; tt < 2; ++tt)
      w2f[s][tt] = *(const short8*)&wsW2[((s * 16 + 2 * wave + tt) * 64 + lane) * 8];
#pragma unroll
  for (int s = 0; s < 8; ++s)
    w3f[s] = *(const short8*)&wsW3[((s * 4 + mt3) * 64 + lane) * 8];

  // ---- biases as fp32 regs (20); b1/b2 pre-scaled; used as acc init ----
  float b1a[2][4], b2a[2][4], b3a[4];
#pragma unroll
  for (int tt = 0; tt < 2; ++tt) {
    float4 v1 = *(const float4*)&b1[(2 * wave + tt) * 16 + q * 4];
    float4 v2 = *(const float4*)&b2[(2 * wave + tt) * 16 + q * 4];
    b1a[tt][0] = v1.x * TSCALE; b1a[tt][1] = v1.y * TSCALE;
    b1a[tt][2] = v1.z * TSCALE; b1a[tt][3] = v1.w * TSCALE;
    b2a[tt][0] = v2.x * TSCALE; b2a[tt][1] = v2.y * TSCALE;
    b2a[tt][2] = v2.z * TSCALE; b2a[tt][3] = v2.w * TSCALE;
  }
  *(float4*)b3a = *(const float4*)&b3[mt3 * 16 + q * 4];

  // ---- frag-layout index bases (loop-invariant) ----
  const int rb  = lane * 8;                                   // read base (shorts); tile adds *512
  const int j0  = 4 * (q & 1);
  // H write: k = (2*wave+tt)*16 + 4q + r -> s = wave, d = (q>>1) + 2*tt
  const int hw0 = (wave * 64 + i15 + 16 * (q >> 1)) * 8 + j0; // +tt*256, +nt*4096
  // Z write: k = mt3*16 + 4q + r -> s = mt3>>1, d = 2*(mt3&1) + (q>>1)
  const int zw0 = ((mt3 >> 1) * 64 + i15 + 16 * (2 * (mt3 & 1) + (q >> 1))) * 8 + j0;  // +nt*1024

  // ---- RK4 state ----
  float z[8], zacc[8];
#pragma unroll
  for (int j = 0; j < 2; ++j) {
    const int nt = 2 * ntp + j;
    float4 v = *(const float4*)&z0[(grow + nt * 16 + i15) * DIM + mt3 * 16 + q * 4];
    z[j * 4 + 0] = v.x; z[j * 4 + 1] = v.y; z[j * 4 + 2] = v.z; z[j * 4 + 3] = v.w;
#pragma unroll
    for (int r = 0; r < 4; ++r) zacc[j * 4 + r] = 0.f;
    uint2 p; p.x = pk2(v.x, v.y); p.y = pk2(v.z, v.w);
    *(uint2*)&Zbuf[zw0 + nt * 1024] = p;
  }

  const float DT6 = DT / 6.0f, DT3 = DT / 3.0f, DTH = 0.5f * DT;

#pragma unroll 1
  for (int it = 0; it < NSTEPS * 4; ++it) {
    const int st = it & 3;
    __syncthreads();  // B1: Zbuf stage visible; prev L3 reads of Hbuf done

    // ---- Layer 1: K=64, acc init = b1 (scaled) ----
    floatx4 acc[2][4];
#pragma unroll
    for (int tt = 0; tt < 2; ++tt)
#pragma unroll
      for (int nt = 0; nt < 4; ++nt)
        acc[tt][nt] = floatx4{b1a[tt][0], b1a[tt][1], b1a[tt][2], b1a[tt][3]};
#pragma unroll
    for (int s = 0; s < 2; ++s)
#pragma unroll
      for (int nt = 0; nt < 4; ++nt) {
        short8 bz = *(const short8*)&Zbuf[rb + (nt * 2 + s) * 512];
        acc[0][nt] = __builtin_amdgcn_mfma_f32_16x16x32_bf16(w1f[s][0], bz, acc[0][nt], 0, 0, 0);
        acc[1][nt] = __builtin_amdgcn_mfma_f32_16x16x32_bf16(w1f[s][1], bz, acc[1][nt], 0, 0, 0);
      }
#pragma unroll
    for (int tt = 0; tt < 2; ++tt)
#pragma unroll
      for (int nt = 0; nt < 4; ++nt) {
        uint2 p;
        p.x = pk2(tanh_pre(acc[tt][nt][0]), tanh_pre(acc[tt][nt][1]));
        p.y = pk2(tanh_pre(acc[tt][nt][2]), tanh_pre(acc[tt][nt][3]));
        *(uint2*)&Hbuf[hw0 + tt * 256 + nt * 4096] = p;
      }
    __syncthreads();  // B2: H1 visible

    // ---- Layer 2: K=256, acc init = b2 (scaled) ----
    floatx4 acc2[2][4];
#pragma unroll
    for (int tt = 0; tt < 2; ++tt)
#pragma unroll
      for (int nt = 0; nt < 4; ++nt)
        acc2[tt][nt] = floatx4{b2a[tt][0], b2a[tt][1], b2a[tt][2], b2a[tt][3]};
#pragma unroll
    for (int s = 0; s < 8; ++s)
#pragma unroll
      for (int nt = 0; nt < 4; ++nt) {
        short8 bh = *(const short8*)&Hbuf[rb + (nt * 8 + s) * 512];
        acc2[0][nt] = __builtin_amdgcn_mfma_f32_16x16x32_bf16(w2f[s][0], bh, acc2[0][nt], 0, 0, 0);
        acc2[1][nt] = __builtin_amdgcn_mfma_f32_16x16x32_bf16(w2f[s][1], bh, acc2[1][nt], 0, 0, 0);
      }
    __syncthreads();  // B3: all H1 reads done -> Hbuf may be overwritten

#pragma unroll
    for (int tt = 0; tt < 2; ++tt)
#pragma unroll
      for (int nt = 0; nt < 4; ++nt) {
        uint2 p;
        p.x = pk2(tanh_pre(acc2[tt][nt][0]), tanh_pre(acc2[tt][nt][1]));
        p.y = pk2(tanh_pre(acc2[tt][nt][2]), tanh_pre(acc2[tt][nt][3]));
        *(uint2*)&Hbuf[hw0 + tt * 256 + nt * 4096] = p;
      }
    __syncthreads();  // B4: H2 visible

    // ---- Layer 3 + RK4: acc init = b3 (unscaled) ----
    floatx4 a3[2];
    a3[0] = floatx4{b3a[0], b3a[1], b3a[2], b3a[3]};
    a3[1] = a3[0];
#pragma unroll
    for (int j = 0; j < 2; ++j) {
      const int nt = 2 * ntp + j;
#pragma unroll
      for (int s = 0; s < 8; ++s) {
        short8 bh = *(const short8*)&Hbuf[rb + (nt * 8 + s) * 512];
        a3[j] = __builtin_amdgcn_mfma_f32_16x16x32_bf16(w3f[s], bh, a3[j], 0, 0, 0);
      }
    }
    const float wsum  = (st == 0 || st == 3) ? DT6 : DT3;
    const float cst   = (st == 2) ? DT : DTH;
    const bool  last  = (st == 3);
    const bool  first = (st == 0);
#pragma unroll
    for (int j = 0; j < 2; ++j) {
      const int nt = 2 * ntp + j;
      float stg[4];
#pragma unroll
      for (int r = 0; r < 4; ++r) {
        const int i = j * 4 + r;
        float k = a3[j][r];
        float za = first ? z[i] : zacc[i];
        za += wsum * k;
        zacc[i] = za;
        if (last) { z[i] = za; stg[r] = za; }
        else      { stg[r] = z[i] + cst * k; }
      }
      uint2 p; p.x = pk2(stg[0], stg[1]); p.y = pk2(stg[2], stg[3]);
      *(uint2*)&Zbuf[zw0 + nt * 1024] = p;
    }
  }

  // ---- final store ----
#pragma unroll
  for (int j = 0; j < 2; ++j) {
    const int nt = 2 * ntp + j;
    float4 v;
    v.x = z[j * 4 + 0]; v.y = z[j * 4 + 1]; v.z = z[j * 4 + 2]; v.w = z[j * 4 + 3];
    *(float4*)&out[(grow + nt * 16 + i15) * DIM + mt3 * 16 + q * 4] = v;
  }
}

extern "C" void kernel_launch(void* const* d_in, const int* in_sizes, int n_in,
                              void* d_out, int out_size, void* d_ws, size_t ws_size,
                              hipStream_t stream) {
  const float* z0 = (const float*)d_in[0];
  const float* W1 = (const float*)d_in[1];
  const float* b1 = (const float*)d_in[2];
  const float* W2 = (const float*)d_in[3];
  const float* b2 = (const float*)d_in[4];
  const float* W3 = (const float*)d_in[5];
  const float* b3 = (const float*)d_in[6];
  unsigned short* ws = (unsigned short*)d_ws;  // 98304 bf16 = 196608 B

  prep_weights<<<384, 256, 0, stream>>>(W1, W2, W3, ws);
  cnf_kernel<<<512, 512, 0, stream>>>(z0, b1, b2, b3, ws, (float*)d_out);
}

// Round 7
// 2878.993 us; speedup vs baseline: 1.9543x; 1.0167x over previous
//
#include <hip/hip_runtime.h>
#include <hip/hip_bf16.h>

#define NSTEPS 100
#define DT (1.0f / 100.0f)
#define TSCALE 2.885390081777927f   // 2*log2(e): folded into W1,W2,b1,b2

typedef __attribute__((ext_vector_type(8))) short short8;   // 8 bf16 (MFMA A/B frag)
typedef __attribute__((ext_vector_type(4))) float floatx4;  // MFMA C/D frag

__device__ __forceinline__ unsigned short f2bf(float f) {
  union { float f; unsigned int u; } v; v.f = f;
  unsigned int u = v.u;
  return (unsigned short)((u + 0x7fffu + ((u >> 16) & 1u)) >> 16);  // RNE
}
// packed f32x2 -> bf16x2 (v_cvt_pk_bf16_f32 on gfx950)
__device__ __forceinline__ unsigned int pk2(float a, float b) {
  __hip_bfloat162 h = __float22bfloat162_rn(make_float2(a, b));
  union { __hip_bfloat162 h; unsigned int u; } v; v.h = h;
  return v.u;
}
// tanh with input pre-scaled by 2*log2(e): tanh = 1 - 2/(2^y + 1)
__device__ __forceinline__ float tanh_pre(float y) {
  float e = __builtin_amdgcn_exp2f(y);
  return 1.0f - 2.0f * __builtin_amdgcn_rcpf(e + 1.0f);
}

// Repack W (K x N row-major fp32) into frag-major bf16 (A-frag of W^T).
// W1/W2 are pre-scaled by TSCALE (tanh input scale folded in).
__global__ void prep_weights(const float* __restrict__ W1,
                             const float* __restrict__ W2,
                             const float* __restrict__ W3,
                             unsigned short* __restrict__ ws) {
  int e = blockIdx.x * 256 + threadIdx.x;  // 98304 total
  const float* src; int N, ntile, el, base; float sc;
  if (e < 16384)      { src = W1; N = 256; ntile = 16; base = 0;     el = e;         sc = TSCALE; }
  else if (e < 81920) { src = W2; N = 256; ntile = 16; base = 16384; el = e - 16384; sc = TSCALE; }
  else                { src = W3; N = 64;  ntile = 4;  base = 81920; el = e - 81920; sc = 1.0f; }
  int j = el & 7;
  int l = (el >> 3) & 63;
  int rem = el >> 9;
  int t = rem % ntile;
  int s = rem / ntile;
  int k = s * 32 + ((l >> 4) << 3) + j;
  int n = t * 16 + (l & 15);
  ws[base + el] = f2bf(src[k * N + n] * sc);
}

// R5 structure (frag-major LDS, register weights) + dual-group software
// pipeline: block owns 128 batch rows as two 64-row groups A/B with private
// LDS buffers, skewed by 2.5 phases. Every barrier interval pairs one
// group's MFMA phase with the other group's tanh epilogue, so each wave
// issues VALU while its own MFMAs/ds_reads are in flight. 5 barriers per
// stage-pair (was 8).
__global__ __launch_bounds__(512, 2)
void cnf_kernel(const float* __restrict__ z0,
                const float* __restrict__ b1,
                const float* __restrict__ b2,
                const float* __restrict__ b3,
                const unsigned short* __restrict__ wsAll,
                float* __restrict__ out) {
  extern __shared__ unsigned short smem[];   // 81920 B
  unsigned short* ZbufA = smem;              //  8192 B (4 nt * 2 s * 512)
  unsigned short* ZbufB = smem + 4096;       //  8192 B
  unsigned short* HbufA = smem + 8192;       // 32768 B (4 nt * 8 s * 512)
  unsigned short* HbufB = smem + 24576;      // 32768 B

  const int tid  = threadIdx.x;
  const int wave = tid >> 6;
  const int lane = tid & 63;
  const int i15  = lane & 15;
  const int q    = lane >> 4;
  const int grow = blockIdx.x * 128;         // group A rows; B = +64
  const int mt3  = wave & 3;                 // L3 M-tile
  const int ntp  = wave >> 2;                // L3 N-pair

  const unsigned short* wsW1 = wsAll;
  const unsigned short* wsW2 = wsAll + 16384;
  const unsigned short* wsW3 = wsAll + 81920;

  // ---- register-resident weight A-frags (112 VGPR) ----
  short8 w1f[2][2], w2f[8][2], w3f[8];
#pragma unroll
  for (int s = 0; s < 2; ++s)
#pragma unroll
    for (int tt = 0; tt < 2; ++tt)
      w1f[s][tt] = *(const short8*)&wsW1[((s * 16 + 2 * wave + tt) * 64 + lane) * 8];
#pragma unroll
  for (int s = 0; s < 8; ++s)
#pragma unroll
    for (int tt = 0; tt < 2; ++tt)
      w2f[s][tt] = *(const short8*)&wsW2[((s * 16 + 2 * wave + tt) * 64 + lane) * 8];
#pragma unroll
  for (int s = 0; s < 8; ++s)
    w3f[s] = *(const short8*)&wsW3[((s * 4 + mt3) * 64 + lane) * 8];

  // ---- biases as fp32 regs (20); b1/b2 pre-scaled; acc init ----
  float b1a[2][4], b2a[2][4], b3a[4];
#pragma unroll
  for (int tt = 0; tt < 2; ++tt) {
    float4 v1 = *(const float4*)&b1[(2 * wave + tt) * 16 + q * 4];
    float4 v2 = *(const float4*)&b2[(2 * wave + tt) * 16 + q * 4];
    b1a[tt][0] = v1.x * TSCALE; b1a[tt][1] = v1.y * TSCALE;
    b1a[tt][2] = v1.z * TSCALE; b1a[tt][3] = v1.w * TSCALE;
    b2a[tt][0] = v2.x * TSCALE; b2a[tt][1] = v2.y * TSCALE;
    b2a[tt][2] = v2.z * TSCALE; b2a[tt][3] = v2.w * TSCALE;
  }
  *(float4*)b3a = *(const float4*)&b3[mt3 * 16 + q * 4];

  // ---- frag-layout index bases ----
  const int rb  = lane * 8;                                   // read base; tile adds *512
  const int j0  = 4 * (q & 1);
  const int hw0 = (wave * 64 + i15 + 16 * (q >> 1)) * 8 + j0; // +tt*256, +nt*4096
  const int zw0 = ((mt3 >> 1) * 64 + i15 + 16 * (2 * (mt3 & 1) + (q >> 1))) * 8 + j0;  // +nt*1024

  // ---- RK4 state, both groups ----
  float zA[8], zaccA[8], zB[8], zaccB[8];
#pragma unroll
  for (int j = 0; j < 2; ++j) {
    const int nt = 2 * ntp + j;
    float4 va = *(const float4*)&z0[(grow + nt * 16 + i15) * 64 + mt3 * 16 + q * 4];
    float4 vb = *(const float4*)&z0[(grow + 64 + nt * 16 + i15) * 64 + mt3 * 16 + q * 4];
    zA[j*4+0]=va.x; zA[j*4+1]=va.y; zA[j*4+2]=va.z; zA[j*4+3]=va.w;
    zB[j*4+0]=vb.x; zB[j*4+1]=vb.y; zB[j*4+2]=vb.z; zB[j*4+3]=vb.w;
#pragma unroll
    for (int r = 0; r < 4; ++r) { zaccA[j*4+r] = 0.f; zaccB[j*4+r] = 0.f; }
    uint2 pa; pa.x = pk2(va.x, va.y); pa.y = pk2(va.z, va.w);
    uint2 pb; pb.x = pk2(vb.x, vb.y); pb.y = pk2(vb.z, vb.w);
    *(uint2*)&ZbufA[zw0 + nt * 1024] = pa;
    *(uint2*)&ZbufB[zw0 + nt * 1024] = pb;
  }

  const float DT6 = DT / 6.0f, DT3 = DT / 3.0f, DTH = 0.5f * DT;

  floatx4 accA[2][4], accB[2][4];

  // ---- phase lambdas ----
  auto phaseP1 = [&](const unsigned short* Z, floatx4 (&a)[2][4]) {
#pragma unroll
    for (int tt = 0; tt < 2; ++tt)
#pragma unroll
      for (int nt = 0; nt < 4; ++nt)
        a[tt][nt] = floatx4{b1a[tt][0], b1a[tt][1], b1a[tt][2], b1a[tt][3]};
#pragma unroll
    for (int s = 0; s < 2; ++s)
#pragma unroll
      for (int nt = 0; nt < 4; ++nt) {
        short8 bz = *(const short8*)&Z[rb + (nt * 2 + s) * 512];
        a[0][nt] = __builtin_amdgcn_mfma_f32_16x16x32_bf16(w1f[s][0], bz, a[0][nt], 0, 0, 0);
        a[1][nt] = __builtin_amdgcn_mfma_f32_16x16x32_bf16(w1f[s][1], bz, a[1][nt], 0, 0, 0);
      }
  };
  auto phaseP2 = [&](const unsigned short* H, floatx4 (&a)[2][4]) {
#pragma unroll
    for (int tt = 0; tt < 2; ++tt)
#pragma unroll
      for (int nt = 0; nt < 4; ++nt)
        a[tt][nt] = floatx4{b2a[tt][0], b2a[tt][1], b2a[tt][2], b2a[tt][3]};
#pragma unroll
    for (int s = 0; s < 8; ++s)
#pragma unroll
      for (int nt = 0; nt < 4; ++nt) {
        short8 bh = *(const short8*)&H[rb + (nt * 8 + s) * 512];
        a[0][nt] = __builtin_amdgcn_mfma_f32_16x16x32_bf16(w2f[s][0], bh, a[0][nt], 0, 0, 0);
        a[1][nt] = __builtin_amdgcn_mfma_f32_16x16x32_bf16(w2f[s][1], bh, a[1][nt], 0, 0, 0);
      }
  };
  auto phaseE = [&](floatx4 (&a)[2][4], unsigned short* H) {
#pragma unroll
    for (int tt = 0; tt < 2; ++tt)
#pragma unroll
      for (int nt = 0; nt < 4; ++nt) {
        uint2 p;
        p.x = pk2(tanh_pre(a[tt][nt][0]), tanh_pre(a[tt][nt][1]));
        p.y = pk2(tanh_pre(a[tt][nt][2]), tanh_pre(a[tt][nt][3]));
        *(uint2*)&H[hw0 + tt * 256 + nt * 4096] = p;
      }
  };
  auto phaseP3 = [&](const unsigned short* H, float (&z)[8], float (&zacc)[8],
                     unsigned short* Z, int st) {
    floatx4 a3[2];
    a3[0] = floatx4{b3a[0], b3a[1], b3a[2], b3a[3]};
    a3[1] = a3[0];
#pragma unroll
    for (int j = 0; j < 2; ++j) {
      const int nt = 2 * ntp + j;
#pragma unroll
      for (int s = 0; s < 8; ++s) {
        short8 bh = *(const short8*)&H[rb + (nt * 8 + s) * 512];
        a3[j] = __builtin_amdgcn_mfma_f32_16x16x32_bf16(w3f[s], bh, a3[j], 0, 0, 0);
      }
    }
    const float wsum  = (st == 0 || st == 3) ? DT6 : DT3;
    const float cst   = (st == 2) ? DT : DTH;
    const bool  last  = (st == 3);
    const bool  first = (st == 0);
#pragma unroll
    for (int j = 0; j < 2; ++j) {
      const int nt = 2 * ntp + j;
      float stg[4];
#pragma unroll
      for (int r = 0; r < 4; ++r) {
        const int i = j * 4 + r;
        float k = a3[j][r];
        float za = first ? z[i] : zacc[i];
        za += wsum * k;
        zacc[i] = za;
        if (last) { z[i] = za; stg[r] = za; }
        else      { stg[r] = z[i] + cst * k; }
      }
      uint2 p; p.x = pk2(stg[0], stg[1]); p.y = pk2(stg[2], stg[3]);
      *(uint2*)&Z[zw0 + nt * 1024] = p;
    }
  };

  // ---- prologue: advance B through P1,E1,P2,E2 of stage 0 ----
  __syncthreads();                 // Zbuf init visible
  phaseP1(ZbufB, accB);
  phaseE(accB, HbufB);
  __syncthreads();
  phaseP2(HbufB, accB);
  __syncthreads();                 // P2 reads done before E2 overwrites
  phaseE(accB, HbufB);
  __syncthreads();

  // ---- steady state: 5 intervals per stage-pair ----
#pragma unroll 1
  for (int it = 0; it < NSTEPS * 4; ++it) {
    const int st = it & 3;
    // k=0: A:P1 | B:P3(stage it)
    phaseP1(ZbufA, accA);
    phaseP3(HbufB, zB, zaccB, ZbufB, st);
    __syncthreads();
    // k=1: B:P1(stage it+1) | A:E1
    phaseP1(ZbufB, accB);
    phaseE(accA, HbufA);
    __syncthreads();
    // k=2: A:P2 | B:E1
    phaseP2(HbufA, accA);
    phaseE(accB, HbufB);
    __syncthreads();
    // k=3: B:P2 | A:E2
    phaseP2(HbufB, accB);
    phaseE(accA, HbufA);
    __syncthreads();
    // k=4: A:P3(stage it) | B:E2
    phaseP3(HbufA, zA, zaccA, ZbufA, st);
    phaseE(accB, HbufB);
    __syncthreads();
  }
  // (B's trailing stage-400 P1..E2 work is harmless: it never runs P3, so
  //  zB/zaccB/ZbufB state is final after it=399 k=0.)

  // ---- final store, both groups ----
#pragma unroll
  for (int j = 0; j < 2; ++j) {
    const int nt = 2 * ntp + j;
    float4 va, vb;
    va.x = zA[j*4+0]; va.y = zA[j*4+1]; va.z = zA[j*4+2]; va.w = zA[j*4+3];
    vb.x = zB[j*4+0]; vb.y = zB[j*4+1]; vb.z = zB[j*4+2]; vb.w = zB[j*4+3];
    *(float4*)&out[(grow + nt * 16 + i15) * 64 + mt3 * 16 + q * 4] = va;
    *(float4*)&out[(grow + 64 + nt * 16 + i15) * 64 + mt3 * 16 + q * 4] = vb;
  }
}

extern "C" void kernel_launch(void* const* d_in, const int* in_sizes, int n_in,
                              void* d_out, int out_size, void* d_ws, size_t ws_size,
                              hipStream_t stream) {
  const float* z0 = (const float*)d_in[0];
  const float* W1 = (const float*)d_in[1];
  const float* b1 = (const float*)d_in[2];
  const float* W2 = (const float*)d_in[3];
  const float* b2 = (const float*)d_in[4];
  const float* W3 = (const float*)d_in[5];
  const float* b3 = (const float*)d_in[6];
  unsigned short* ws = (unsigned short*)d_ws;  // 98304 bf16 = 196608 B

  prep_weights<<<384, 256, 0, stream>>>(W1, W2, W3, ws);
  (void)hipFuncSetAttribute((const void*)cnf_kernel,
                            hipFuncAttributeMaxDynamicSharedMemorySize, 81920);
  cnf_kernel<<<256, 512, 81920, stream>>>(z0, b1, b2, b3, ws, (float*)d_out);
}

// Round 8
// 2856.398 us; speedup vs baseline: 1.9698x; 1.0079x over previous
//
#include <hip/hip_runtime.h>
#include <hip/hip_bf16.h>

#define NSTEPS 100
#define DT (1.0f / 100.0f)
#define TSCALE 2.885390081777927f   // 2*log2(e): folded into W1,W2,b1,b2

typedef __attribute__((ext_vector_type(8))) short short8;   // 8 bf16 (MFMA A/B frag)
typedef __attribute__((ext_vector_type(4))) float floatx4;  // MFMA C/D frag

__device__ __forceinline__ unsigned short f2bf(float f) {
  union { float f; unsigned int u; } v; v.f = f;
  unsigned int u = v.u;
  return (unsigned short)((u + 0x7fffu + ((u >> 16) & 1u)) >> 16);  // RNE
}
// packed f32x2 -> bf16x2 (v_cvt_pk_bf16_f32 on gfx950)
__device__ __forceinline__ unsigned int pk2(float a, float b) {
  __hip_bfloat162 h = __float22bfloat162_rn(make_float2(a, b));
  union { __hip_bfloat162 h; unsigned int u; } v; v.h = h;
  return v.u;
}
// tanh with input pre-scaled by 2*log2(e): tanh = 1 - 2/(2^y + 1)
__device__ __forceinline__ float tanh_pre(float y) {
  float e = __builtin_amdgcn_exp2f(y);
  return 1.0f - 2.0f * __builtin_amdgcn_rcpf(e + 1.0f);
}

// Repack W (K x N row-major fp32) into frag-major bf16 (A-frag of W^T).
// W1/W2 are pre-scaled by TSCALE (tanh input scale folded in).
__global__ void prep_weights(const float* __restrict__ W1,
                             const float* __restrict__ W2,
                             const float* __restrict__ W3,
                             unsigned short* __restrict__ ws) {
  int e = blockIdx.x * 256 + threadIdx.x;  // 98304 total
  const float* src; int N, ntile, el, base; float sc;
  if (e < 16384)      { src = W1; N = 256; ntile = 16; base = 0;     el = e;         sc = TSCALE; }
  else if (e < 81920) { src = W2; N = 256; ntile = 16; base = 16384; el = e - 16384; sc = TSCALE; }
  else                { src = W3; N = 64;  ntile = 4;  base = 81920; el = e - 81920; sc = 1.0f; }
  int j = el & 7;
  int l = (el >> 3) & 63;
  int rem = el >> 9;
  int t = rem % ntile;
  int s = rem / ntile;
  int k = s * 32 + ((l >> 4) << 3) + j;
  int n = t * 16 + (l & 15);
  ws[base + el] = f2bf(src[k * N + n] * sc);
}

// Dual-group software pipeline (R6) with the spill fixed:
// W2 (the hot 64-reg set) stays register-resident; W1 and W3 live in LDS
// frag-major (loaded once, wave-contiguous b128 reads, immediate offsets,
// zero conflicts). Core reg set ~180 -> no scratch.
// Block owns 128 batch rows as groups A/B with private LDS buffers, skewed
// 2.5 phases; every barrier interval pairs one group's MFMA phase with the
// other group's tanh epilogue.
__global__ __launch_bounds__(512, 2)
void cnf_kernel(const float* __restrict__ z0,
                const float* __restrict__ b1,
                const float* __restrict__ b2,
                const float* __restrict__ b3,
                const unsigned short* __restrict__ wsAll,
                float* __restrict__ out) {
  extern __shared__ unsigned short smem[];   // 147456 B
  unsigned short* ZbufA = smem;              //  8192 B (4 nt * 2 s * 512)
  unsigned short* ZbufB = smem + 4096;
  unsigned short* HbufA = smem + 8192;       // 32768 B (4 nt * 8 s * 512)
  unsigned short* HbufB = smem + 24576;
  unsigned short* LW1   = smem + 40960;      // 32768 B (frag-major W1)
  unsigned short* LW3   = smem + 57344;      // 32768 B (frag-major W3)

  const int tid  = threadIdx.x;
  const int wave = tid >> 6;
  const int lane = tid & 63;
  const int i15  = lane & 15;
  const int q    = lane >> 4;
  const int grow = blockIdx.x * 128;         // group A rows; B = +64
  const int mt3  = wave & 3;                 // L3 M-tile
  const int ntp  = wave >> 2;                // L3 N-pair

  const unsigned short* wsW1 = wsAll;
  const unsigned short* wsW2 = wsAll + 16384;
  const unsigned short* wsW3 = wsAll + 81920;

  // ---- W1/W3 -> LDS (once) ----
  {
    const uint4* s1 = (const uint4*)wsW1;   // 2048 uint4
    const uint4* s3 = (const uint4*)wsW3;
    uint4* d1 = (uint4*)LW1;
    uint4* d3 = (uint4*)LW3;
#pragma unroll
    for (int i = 0; i < 4; ++i) { d1[tid + 512 * i] = s1[tid + 512 * i];
                                  d3[tid + 512 * i] = s3[tid + 512 * i]; }
  }

  // ---- register-resident W2 A-frags (64 VGPR) ----
  short8 w2f[8][2];
#pragma unroll
  for (int s = 0; s < 8; ++s)
#pragma unroll
    for (int tt = 0; tt < 2; ++tt)
      w2f[s][tt] = *(const short8*)&wsW2[((s * 16 + 2 * wave + tt) * 64 + lane) * 8];

  // ---- biases as fp32 regs (20); b1/b2 pre-scaled; acc init ----
  float b1a[2][4], b2a[2][4], b3a[4];
#pragma unroll
  for (int tt = 0; tt < 2; ++tt) {
    float4 v1 = *(const float4*)&b1[(2 * wave + tt) * 16 + q * 4];
    float4 v2 = *(const float4*)&b2[(2 * wave + tt) * 16 + q * 4];
    b1a[tt][0] = v1.x * TSCALE; b1a[tt][1] = v1.y * TSCALE;
    b1a[tt][2] = v1.z * TSCALE; b1a[tt][3] = v1.w * TSCALE;
    b2a[tt][0] = v2.x * TSCALE; b2a[tt][1] = v2.y * TSCALE;
    b2a[tt][2] = v2.z * TSCALE; b2a[tt][3] = v2.w * TSCALE;
  }
  *(float4*)b3a = *(const float4*)&b3[mt3 * 16 + q * 4];

  // ---- frag-layout index bases ----
  const int rb  = lane * 8;                                   // act read base; tile adds *512
  const int j0  = 4 * (q & 1);
  const int hw0 = (wave * 64 + i15 + 16 * (q >> 1)) * 8 + j0; // +tt*256, +nt*4096
  const int zw0 = ((mt3 >> 1) * 64 + i15 + 16 * (2 * (mt3 & 1) + (q >> 1))) * 8 + j0;  // +nt*1024
  const int w1b = wave * 1024 + lane * 8;                     // + s*8192 + tt*512
  const int w3b = mt3 * 512 + lane * 8;                       // + s*2048

  // ---- RK4 state, both groups ----
  float zA[8], zaccA[8], zB[8], zaccB[8];
#pragma unroll
  for (int j = 0; j < 2; ++j) {
    const int nt = 2 * ntp + j;
    float4 va = *(const float4*)&z0[(grow + nt * 16 + i15) * 64 + mt3 * 16 + q * 4];
    float4 vb = *(const float4*)&z0[(grow + 64 + nt * 16 + i15) * 64 + mt3 * 16 + q * 4];
    zA[j*4+0]=va.x; zA[j*4+1]=va.y; zA[j*4+2]=va.z; zA[j*4+3]=va.w;
    zB[j*4+0]=vb.x; zB[j*4+1]=vb.y; zB[j*4+2]=vb.z; zB[j*4+3]=vb.w;
#pragma unroll
    for (int r = 0; r < 4; ++r) { zaccA[j*4+r] = 0.f; zaccB[j*4+r] = 0.f; }
    uint2 pa; pa.x = pk2(va.x, va.y); pa.y = pk2(va.z, va.w);
    uint2 pb; pb.x = pk2(vb.x, vb.y); pb.y = pk2(vb.z, vb.w);
    *(uint2*)&ZbufA[zw0 + nt * 1024] = pa;
    *(uint2*)&ZbufB[zw0 + nt * 1024] = pb;
  }

  const float DT6 = DT / 6.0f, DT3 = DT / 3.0f, DTH = 0.5f * DT;

  floatx4 accA[2][4], accB[2][4];

  // ---- phase lambdas ----
  auto phaseP1 = [&](const unsigned short* Z, floatx4 (&a)[2][4]) {
#pragma unroll
    for (int tt = 0; tt < 2; ++tt)
#pragma unroll
      for (int nt = 0; nt < 4; ++nt)
        a[tt][nt] = floatx4{b1a[tt][0], b1a[tt][1], b1a[tt][2], b1a[tt][3]};
#pragma unroll
    for (int s = 0; s < 2; ++s) {
      short8 wf0 = *(const short8*)&LW1[w1b + s * 8192];
      short8 wf1 = *(const short8*)&LW1[w1b + s * 8192 + 512];
#pragma unroll
      for (int nt = 0; nt < 4; ++nt) {
        short8 bz = *(const short8*)&Z[rb + (nt * 2 + s) * 512];
        a[0][nt] = __builtin_amdgcn_mfma_f32_16x16x32_bf16(wf0, bz, a[0][nt], 0, 0, 0);
        a[1][nt] = __builtin_amdgcn_mfma_f32_16x16x32_bf16(wf1, bz, a[1][nt], 0, 0, 0);
      }
    }
  };
  auto phaseP2 = [&](const unsigned short* H, floatx4 (&a)[2][4]) {
#pragma unroll
    for (int tt = 0; tt < 2; ++tt)
#pragma unroll
      for (int nt = 0; nt < 4; ++nt)
        a[tt][nt] = floatx4{b2a[tt][0], b2a[tt][1], b2a[tt][2], b2a[tt][3]};
#pragma unroll
    for (int s = 0; s < 8; ++s)
#pragma unroll
      for (int nt = 0; nt < 4; ++nt) {
        short8 bh = *(const short8*)&H[rb + (nt * 8 + s) * 512];
        a[0][nt] = __builtin_amdgcn_mfma_f32_16x16x32_bf16(w2f[s][0], bh, a[0][nt], 0, 0, 0);
        a[1][nt] = __builtin_amdgcn_mfma_f32_16x16x32_bf16(w2f[s][1], bh, a[1][nt], 0, 0, 0);
      }
  };
  auto phaseE = [&](floatx4 (&a)[2][4], unsigned short* H) {
#pragma unroll
    for (int tt = 0; tt < 2; ++tt)
#pragma unroll
      for (int nt = 0; nt < 4; ++nt) {
        uint2 p;
        p.x = pk2(tanh_pre(a[tt][nt][0]), tanh_pre(a[tt][nt][1]));
        p.y = pk2(tanh_pre(a[tt][nt][2]), tanh_pre(a[tt][nt][3]));
        *(uint2*)&H[hw0 + tt * 256 + nt * 4096] = p;
      }
  };
  auto phaseP3 = [&](const unsigned short* H, float (&z)[8], float (&zacc)[8],
                     unsigned short* Z, int st) {
    floatx4 a3[2];
    a3[0] = floatx4{b3a[0], b3a[1], b3a[2], b3a[3]};
    a3[1] = a3[0];
#pragma unroll
    for (int s = 0; s < 8; ++s) {
      short8 wf = *(const short8*)&LW3[w3b + s * 2048];
#pragma unroll
      for (int j = 0; j < 2; ++j) {
        short8 bh = *(const short8*)&H[rb + ((2 * ntp + j) * 8 + s) * 512];
        a3[j] = __builtin_amdgcn_mfma_f32_16x16x32_bf16(wf, bh, a3[j], 0, 0, 0);
      }
    }
    const float wsum  = (st == 0 || st == 3) ? DT6 : DT3;
    const float cst   = (st == 2) ? DT : DTH;
    const bool  last  = (st == 3);
    const bool  first = (st == 0);
#pragma unroll
    for (int j = 0; j < 2; ++j) {
      const int nt = 2 * ntp + j;
      float stg[4];
#pragma unroll
      for (int r = 0; r < 4; ++r) {
        const int i = j * 4 + r;
        float k = a3[j][r];
        float za = first ? z[i] : zacc[i];
        za += wsum * k;
        zacc[i] = za;
        if (last) { z[i] = za; stg[r] = za; }
        else      { stg[r] = z[i] + cst * k; }
      }
      uint2 p; p.x = pk2(stg[0], stg[1]); p.y = pk2(stg[2], stg[3]);
      *(uint2*)&Z[zw0 + nt * 1024] = p;
    }
  };

  // ---- prologue: advance B through P1,E1,P2,E2 of stage 0 ----
  __syncthreads();                 // Zbuf init + LW1/LW3 visible
  phaseP1(ZbufB, accB);
  phaseE(accB, HbufB);
  __syncthreads();
  phaseP2(HbufB, accB);
  __syncthreads();                 // P2 reads done before E2 overwrites
  phaseE(accB, HbufB);
  __syncthreads();

  // ---- steady state: 5 intervals per stage-pair ----
#pragma unroll 1
  for (int it = 0; it < NSTEPS * 4; ++it) {
    const int st = it & 3;
    // k=0: A:P1 | B:P3(stage it)
    phaseP1(ZbufA, accA);
    phaseP3(HbufB, zB, zaccB, ZbufB, st);
    __syncthreads();
    // k=1: B:P1(stage it+1) | A:E1
    phaseP1(ZbufB, accB);
    phaseE(accA, HbufA);
    __syncthreads();
    // k=2: A:P2 | B:E1
    phaseP2(HbufA, accA);
    phaseE(accB, HbufB);
    __syncthreads();
    // k=3: B:P2 | A:E2
    phaseP2(HbufB, accB);
    phaseE(accA, HbufA);
    __syncthreads();
    // k=4: A:P3(stage it) | B:E2
    phaseP3(HbufA, zA, zaccA, ZbufA, st);
    phaseE(accB, HbufB);
    __syncthreads();
  }
  // (B's trailing stage-400 P1/P2/E work never runs P3, so zB is final.)

  // ---- final store, both groups ----
#pragma unroll
  for (int j = 0; j < 2; ++j) {
    const int nt = 2 * ntp + j;
    float4 va, vb;
    va.x = zA[j*4+0]; va.y = zA[j*4+1]; va.z = zA[j*4+2]; va.w = zA[j*4+3];
    vb.x = zB[j*4+0]; vb.y = zB[j*4+1]; vb.z = zB[j*4+2]; vb.w = zB[j*4+3];
    *(float4*)&out[(grow + nt * 16 + i15) * 64 + mt3 * 16 + q * 4] = va;
    *(float4*)&out[(grow + 64 + nt * 16 + i15) * 64 + mt3 * 16 + q * 4] = vb;
  }
}

extern "C" void kernel_launch(void* const* d_in, const int* in_sizes, int n_in,
                              void* d_out, int out_size, void* d_ws, size_t ws_size,
                              hipStream_t stream) {
  const float* z0 = (const float*)d_in[0];
  const float* W1 = (const float*)d_in[1];
  const float* b1 = (const float*)d_in[2];
  const float* W2 = (const float*)d_in[3];
  const float* b2 = (const float*)d_in[4];
  const float* W3 = (const float*)d_in[5];
  const float* b3 = (const float*)d_in[6];
  unsigned short* ws = (unsigned short*)d_ws;  // 98304 bf16 = 196608 B

  prep_weights<<<384, 256, 0, stream>>>(W1, W2, W3, ws);
  (void)hipFuncSetAttribute((const void*)cnf_kernel,
                            hipFuncAttributeMaxDynamicSharedMemorySize, 147456);
  cnf_kernel<<<256, 512, 147456, stream>>>(z0, b1, b2, b3, ws, (float*)d_out);
}

// Round 9
// 2805.366 us; speedup vs baseline: 2.0056x; 1.0182x over previous
//
#include <hip/hip_runtime.h>
#include <hip/hip_bf16.h>

#define NSTEPS 100
#define DT (1.0f / 100.0f)
#define TSCALE 2.885390081777927f   // 2*log2(e): folded into W1,W2,b1,b2

typedef __attribute__((ext_vector_type(8))) short short8;   // 8 bf16 (MFMA A/B frag)
typedef __attribute__((ext_vector_type(4))) float floatx4;  // MFMA C/D frag

__device__ __forceinline__ unsigned short f2bf(float f) {
  union { float f; unsigned int u; } v; v.f = f;
  unsigned int u = v.u;
  return (unsigned short)((u + 0x7fffu + ((u >> 16) & 1u)) >> 16);  // RNE
}
__device__ __forceinline__ unsigned int pk2(float a, float b) {
  __hip_bfloat162 h = __float22bfloat162_rn(make_float2(a, b));
  union { __hip_bfloat162 h; unsigned int u; } v; v.h = h;
  return v.u;
}
// tanh with input pre-scaled by 2*log2(e): tanh = 1 - 2/(2^y + 1)
__device__ __forceinline__ float tanh_pre(float y) {
  float e = __builtin_amdgcn_exp2f(y);
  return 1.0f - 2.0f * __builtin_amdgcn_rcpf(e + 1.0f);
}

// Repack W (K x N row-major fp32) into frag-major bf16 (A-frag of W^T).
// W1/W2 are pre-scaled by TSCALE (tanh input scale folded in).
__global__ void prep_weights(const float* __restrict__ W1,
                             const float* __restrict__ W2,
                             const float* __restrict__ W3,
                             unsigned short* __restrict__ ws) {
  int e = blockIdx.x * 256 + threadIdx.x;  // 98304 total
  const float* src; int N, ntile, el, base; float sc;
  if (e < 16384)      { src = W1; N = 256; ntile = 16; base = 0;     el = e;         sc = TSCALE; }
  else if (e < 81920) { src = W2; N = 256; ntile = 16; base = 16384; el = e - 16384; sc = TSCALE; }
  else                { src = W3; N = 64;  ntile = 4;  base = 81920; el = e - 81920; sc = 1.0f; }
  int j = el & 7;
  int l = (el >> 3) & 63;
  int rem = el >> 9;
  int t = rem % ntile;
  int s = rem / ntile;
  int k = s * 32 + ((l >> 4) << 3) + j;
  int n = t * 16 + (l & 15);
  ws[base + el] = f2bf(src[k * N + n] * sc);
}

// Dual-group pipeline (R7 dataflow/barriers) with MFMA and tanh streams
// fused at statement granularity: every unrolled step issues one group's
// MFMAs immediately followed by the other group's tanh+pack, so each
// wave's in-order stream co-fills the matrix and vector pipes.
// W2 register-resident; W1/W3 in LDS frag-major (b128, immediate offsets).
__global__ __launch_bounds__(512, 2)
void cnf_kernel(const float* __restrict__ z0,
                const float* __restrict__ b1,
                const float* __restrict__ b2,
                const float* __restrict__ b3,
                const unsigned short* __restrict__ wsAll,
                float* __restrict__ out) {
  extern __shared__ unsigned short smem[];   // 147456 B
  unsigned short* ZbufA = smem;              //  8192 B (4 nt * 2 s * 512)
  unsigned short* ZbufB = smem + 4096;
  unsigned short* HbufA = smem + 8192;       // 32768 B (4 nt * 8 s * 512)
  unsigned short* HbufB = smem + 24576;
  unsigned short* LW1   = smem + 40960;      // 32768 B (frag-major W1)
  unsigned short* LW3   = smem + 57344;      // 32768 B (frag-major W3)

  const int tid  = threadIdx.x;
  const int wave = tid >> 6;
  const int lane = tid & 63;
  const int i15  = lane & 15;
  const int q    = lane >> 4;
  const int grow = blockIdx.x * 128;         // group A rows; B = +64
  const int mt3  = wave & 3;                 // L3 M-tile
  const int ntp  = wave >> 2;                // L3 N-pair

  const unsigned short* wsW1 = wsAll;
  const unsigned short* wsW2 = wsAll + 16384;
  const unsigned short* wsW3 = wsAll + 81920;

  // ---- W1/W3 -> LDS (once) ----
  {
    const uint4* s1 = (const uint4*)wsW1;
    const uint4* s3 = (const uint4*)wsW3;
    uint4* d1 = (uint4*)LW1;
    uint4* d3 = (uint4*)LW3;
#pragma unroll
    for (int i = 0; i < 4; ++i) { d1[tid + 512 * i] = s1[tid + 512 * i];
                                  d3[tid + 512 * i] = s3[tid + 512 * i]; }
  }

  // ---- register-resident W2 A-frags (64 VGPR) ----
  short8 w2f[8][2];
#pragma unroll
  for (int s = 0; s < 8; ++s)
#pragma unroll
    for (int tt = 0; tt < 2; ++tt)
      w2f[s][tt] = *(const short8*)&wsW2[((s * 16 + 2 * wave + tt) * 64 + lane) * 8];

  // ---- biases as fp32 regs (20); b1/b2 pre-scaled; acc init ----
  float b1a[2][4], b2a[2][4], b3a[4];
#pragma unroll
  for (int tt = 0; tt < 2; ++tt) {
    float4 v1 = *(const float4*)&b1[(2 * wave + tt) * 16 + q * 4];
    float4 v2 = *(const float4*)&b2[(2 * wave + tt) * 16 + q * 4];
    b1a[tt][0] = v1.x * TSCALE; b1a[tt][1] = v1.y * TSCALE;
    b1a[tt][2] = v1.z * TSCALE; b1a[tt][3] = v1.w * TSCALE;
    b2a[tt][0] = v2.x * TSCALE; b2a[tt][1] = v2.y * TSCALE;
    b2a[tt][2] = v2.z * TSCALE; b2a[tt][3] = v2.w * TSCALE;
  }
  *(float4*)b3a = *(const float4*)&b3[mt3 * 16 + q * 4];

  // ---- frag-layout index bases ----
  const int rb  = lane * 8;                                   // act read base; tile adds *512
  const int j0  = 4 * (q & 1);
  const int hw0 = (wave * 64 + i15 + 16 * (q >> 1)) * 8 + j0; // +tt*256, +nt*4096
  const int zw0 = ((mt3 >> 1) * 64 + i15 + 16 * (2 * (mt3 & 1) + (q >> 1))) * 8 + j0;  // +nt*1024
  const int w1b = wave * 1024 + lane * 8;                     // + s*8192 + tt*512
  const int w3b = mt3 * 512 + lane * 8;                       // + s*2048

  // ---- RK4 state, both groups ----
  float zA[8], zaccA[8], zB[8], zaccB[8];
#pragma unroll
  for (int j = 0; j < 2; ++j) {
    const int nt = 2 * ntp + j;
    float4 va = *(const float4*)&z0[(grow + nt * 16 + i15) * 64 + mt3 * 16 + q * 4];
    float4 vb = *(const float4*)&z0[(grow + 64 + nt * 16 + i15) * 64 + mt3 * 16 + q * 4];
    zA[j*4+0]=va.x; zA[j*4+1]=va.y; zA[j*4+2]=va.z; zA[j*4+3]=va.w;
    zB[j*4+0]=vb.x; zB[j*4+1]=vb.y; zB[j*4+2]=vb.z; zB[j*4+3]=vb.w;
#pragma unroll
    for (int r = 0; r < 4; ++r) { zaccA[j*4+r] = 0.f; zaccB[j*4+r] = 0.f; }
    uint2 pa; pa.x = pk2(va.x, va.y); pa.y = pk2(va.z, va.w);
    uint2 pb; pb.x = pk2(vb.x, vb.y); pb.y = pk2(vb.z, vb.w);
    *(uint2*)&ZbufA[zw0 + nt * 1024] = pa;
    *(uint2*)&ZbufB[zw0 + nt * 1024] = pb;
  }

  const float DT6 = DT / 6.0f, DT3 = DT / 3.0f, DTH = 0.5f * DT;

  floatx4 accA[2][4], accB[2][4];

  // ---- helpers ----
  auto initAcc = [&](floatx4 (&a)[2][4], float (&b)[2][4]) {
#pragma unroll
    for (int tt = 0; tt < 2; ++tt)
#pragma unroll
      for (int nt = 0; nt < 4; ++nt)
        a[tt][nt] = floatx4{b[tt][0], b[tt][1], b[tt][2], b[tt][3]};
  };
  // one-eighth of an epilogue: 4 tanh + 2 packs + 1 b64 write
  auto ePart = [&](int u, floatx4 (&a)[2][4], unsigned short* H) {
    const int tt = u >> 2, nt = u & 3;
    uint2 p;
    p.x = pk2(tanh_pre(a[tt][nt][0]), tanh_pre(a[tt][nt][1]));
    p.y = pk2(tanh_pre(a[tt][nt][2]), tanh_pre(a[tt][nt][3]));
    *(uint2*)&H[hw0 + tt * 256 + nt * 4096] = p;
  };
  // one step of L1 (pair u: s=u>>2, nt=u&3): 2 MFMAs
  auto p1Step = [&](int u, const unsigned short* Z, floatx4 (&a)[2][4]) {
    const int s = u >> 2, nt = u & 3;
    short8 wa = *(const short8*)&LW1[w1b + s * 8192];
    short8 wb = *(const short8*)&LW1[w1b + s * 8192 + 512];
    short8 bz = *(const short8*)&Z[rb + (nt * 2 + s) * 512];
    a[0][nt] = __builtin_amdgcn_mfma_f32_16x16x32_bf16(wa, bz, a[0][nt], 0, 0, 0);
    a[1][nt] = __builtin_amdgcn_mfma_f32_16x16x32_bf16(wb, bz, a[1][nt], 0, 0, 0);
  };
  // one s-step of L3: 2 MFMAs
  auto p3Step = [&](int s, const unsigned short* H, floatx4 (&a3)[2]) {
    short8 wf = *(const short8*)&LW3[w3b + s * 2048];
    short8 b0 = *(const short8*)&H[rb + (ntp * 16 + s) * 512];
    short8 b1_ = *(const short8*)&H[rb + (ntp * 16 + 8 + s) * 512];
    a3[0] = __builtin_amdgcn_mfma_f32_16x16x32_bf16(wf, b0, a3[0], 0, 0, 0);
    a3[1] = __builtin_amdgcn_mfma_f32_16x16x32_bf16(wf, b1_, a3[1], 0, 0, 0);
  };
  auto rk4Tail = [&](floatx4 (&a3)[2], float (&z)[8], float (&zacc)[8],
                     unsigned short* Z, int st) {
    const float wsum  = (st == 0 || st == 3) ? DT6 : DT3;
    const float cst   = (st == 2) ? DT : DTH;
    const bool  last  = (st == 3);
    const bool  first = (st == 0);
#pragma unroll
    for (int j = 0; j < 2; ++j) {
      const int nt = 2 * ntp + j;
      float stg[4];
#pragma unroll
      for (int r = 0; r < 4; ++r) {
        const int i = j * 4 + r;
        float k = a3[j][r];
        float za = first ? z[i] : zacc[i];
        za += wsum * k;
        zacc[i] = za;
        if (last) { z[i] = za; stg[r] = za; }
        else      { stg[r] = z[i] + cst * k; }
      }
      uint2 p; p.x = pk2(stg[0], stg[1]); p.y = pk2(stg[2], stg[3]);
      *(uint2*)&Z[zw0 + nt * 1024] = p;
    }
  };

  // ---- prologue: advance B through P1,E1,P2,E2 of stage 0 (unfused) ----
  __syncthreads();                 // Zbuf init + LW1/LW3 visible
  initAcc(accB, b1a);
#pragma unroll
  for (int u = 0; u < 8; ++u) p1Step(u, ZbufB, accB);
#pragma unroll
  for (int u = 0; u < 8; ++u) ePart(u, accB, HbufB);
  __syncthreads();
  initAcc(accB, b2a);
#pragma unroll
  for (int s = 0; s < 8; ++s)
#pragma unroll
    for (int nt = 0; nt < 4; ++nt) {
      short8 bh = *(const short8*)&HbufB[rb + (nt * 8 + s) * 512];
      accB[0][nt] = __builtin_amdgcn_mfma_f32_16x16x32_bf16(w2f[s][0], bh, accB[0][nt], 0, 0, 0);
      accB[1][nt] = __builtin_amdgcn_mfma_f32_16x16x32_bf16(w2f[s][1], bh, accB[1][nt], 0, 0, 0);
    }
  __syncthreads();
#pragma unroll
  for (int u = 0; u < 8; ++u) ePart(u, accB, HbufB);
  __syncthreads();

  // ---- steady state: 5 intervals per it, MFMA⇄VALU fused per step ----
#pragma unroll 1
  for (int it = 0; it < NSTEPS * 4; ++it) {
    const int st = it & 3;

    // k=0: A:P1 (16 MFMA) fused with B:P3 (16 MFMA) + B RK4 tail
    {
      initAcc(accA, b1a);
      floatx4 a3[2];
      a3[0] = floatx4{b3a[0], b3a[1], b3a[2], b3a[3]};
      a3[1] = a3[0];
#pragma unroll
      for (int u = 0; u < 8; ++u) {
        p3Step(u, HbufB, a3);
        p1Step(u, ZbufA, accA);
      }
      rk4Tail(a3, zB, zaccB, ZbufB, st);
    }
    __syncthreads();

    // k=1: B:P1 (16 MFMA) fused with A:E1 (32 tanh)
    {
      initAcc(accB, b1a);
#pragma unroll
      for (int u = 0; u < 8; ++u) {
        p1Step(u, ZbufB, accB);
        ePart(u, accA, HbufA);
      }
    }
    __syncthreads();

    // k=2: A:P2 (64 MFMA) fused with B:E1 (32 tanh)
    {
      initAcc(accA, b2a);
#pragma unroll
      for (int s = 0; s < 8; ++s) {
#pragma unroll
        for (int nt = 0; nt < 4; ++nt) {
          short8 bh = *(const short8*)&HbufA[rb + (nt * 8 + s) * 512];
          accA[0][nt] = __builtin_amdgcn_mfma_f32_16x16x32_bf16(w2f[s][0], bh, accA[0][nt], 0, 0, 0);
          accA[1][nt] = __builtin_amdgcn_mfma_f32_16x16x32_bf16(w2f[s][1], bh, accA[1][nt], 0, 0, 0);
        }
        ePart(s, accB, HbufB);
      }
    }
    __syncthreads();

    // k=3: B:P2 (64 MFMA) fused with A:E2 (32 tanh)
    {
      initAcc(accB, b2a);
#pragma unroll
      for (int s = 0; s < 8; ++s) {
#pragma unroll
        for (int nt = 0; nt < 4; ++nt) {
          short8 bh = *(const short8*)&HbufB[rb + (nt * 8 + s) * 512];
          accB[0][nt] = __builtin_amdgcn_mfma_f32_16x16x32_bf16(w2f[s][0], bh, accB[0][nt], 0, 0, 0);
          accB[1][nt] = __builtin_amdgcn_mfma_f32_16x16x32_bf16(w2f[s][1], bh, accB[1][nt], 0, 0, 0);
        }
        ePart(s, accA, HbufA);
      }
    }
    __syncthreads();

    // k=4: A:P3 (16 MFMA) + A RK4, fused with B:E2 (32 tanh)
    {
      floatx4 a3[2];
      a3[0] = floatx4{b3a[0], b3a[1], b3a[2], b3a[3]};
      a3[1] = a3[0];
#pragma unroll
      for (int u = 0; u < 8; ++u) {
        p3Step(u, HbufA, a3);
        ePart(u, accB, HbufB);
      }
      rk4Tail(a3, zA, zaccA, ZbufA, st);
    }
    __syncthreads();
  }
  // (B's trailing stage-400 P1/P2/E work never runs P3, so zB is final.)

  // ---- final store, both groups ----
#pragma unroll
  for (int j = 0; j < 2; ++j) {
    const int nt = 2 * ntp + j;
    float4 va, vb;
    va.x = zA[j*4+0]; va.y = zA[j*4+1]; va.z = zA[j*4+2]; va.w = zA[j*4+3];
    vb.x = zB[j*4+0]; vb.y = zB[j*4+1]; vb.z = zB[j*4+2]; vb.w = zB[j*4+3];
    *(float4*)&out[(grow + nt * 16 + i15) * 64 + mt3 * 16 + q * 4] = va;
    *(float4*)&out[(grow + 64 + nt * 16 + i15) * 64 + mt3 * 16 + q * 4] = vb;
  }
}

extern "C" void kernel_launch(void* const* d_in, const int* in_sizes, int n_in,
                              void* d_out, int out_size, void* d_ws, size_t ws_size,
                              hipStream_t stream) {
  const float* z0 = (const float*)d_in[0];
  const float* W1 = (const float*)d_in[1];
  const float* b1 = (const float*)d_in[2];
  const float* W2 = (const float*)d_in[3];
  const float* b2 = (const float*)d_in[4];
  const float* W3 = (const float*)d_in[5];
  const float* b3 = (const float*)d_in[6];
  unsigned short* ws = (unsigned short*)d_ws;  // 98304 bf16 = 196608 B

  prep_weights<<<384, 256, 0, stream>>>(W1, W2, W3, ws);
  (void)hipFuncSetAttribute((const void*)cnf_kernel,
                            hipFuncAttributeMaxDynamicSharedMemorySize, 147456);
  cnf_kernel<<<256, 512, 147456, stream>>>(z0, b1, b2, b3, ws, (float*)d_out);
}